// Round 15
// baseline (1314.634 us; speedup 1.0000x reference)
//
#include <hip/hip_runtime.h>
#include <math.h>

typedef unsigned short u16;
typedef __attribute__((ext_vector_type(8))) short    bf16x8;
typedef __attribute__((ext_vector_type(8))) unsigned short u16x8;
typedef __attribute__((ext_vector_type(4))) float    f32x4;
typedef __attribute__((ext_vector_type(16))) float   f32x16;

// Problem constants
#define NB   32        // batch
#define NC   256       // in channels
#define NO   256       // out channels
#define NH   56
#define NW   56
#define NP   3136      // H*W
#define NE   8
#define NID  64
#define HP   58        // padded rows
#define WP   64        // padded row width (aligned)

// Workspace layout (bytes)
#define WMIX_OFF   0                    // u16 [32][9][256][256] = 37,748,736 B
#define XPT_OFF    37748736             // u16 [32][58][64][256] = 60,817,408 B
#define POOL_OFF   98566144             // f32 [32][256]
#define RBUF_OFF   98598912             // f32 [32][8]

__device__ __forceinline__ u16 f2bf(float f) {
    unsigned u = __float_as_uint(f);
    unsigned r = (u + 0x7FFFu + ((u >> 16) & 1u)) >> 16;   // RNE
    return (u16)r;
}

__device__ __forceinline__ void gl_lds16(const void* g, void* l) {
    __builtin_amdgcn_global_load_lds(
        (const __attribute__((address_space(1))) unsigned int*)g,
        (__attribute__((address_space(3))) unsigned int*)l, 16, 0, 0);
}

#define SBAR() __builtin_amdgcn_sched_barrier(0);
// counted wait (perf hint only; correctness is register-dep guaranteed)
#define VM_WAIT(N) { asm volatile("s_waitcnt vmcnt(" #N ")" ::: "memory"); \
                     __builtin_amdgcn_sched_barrier(0); }

// ---------------------------------------------------------------- kernel 0
// Zero pooled accumulators + the two border rows (h'=0,57) of xpadT.
__global__ __launch_bounds__(256) void zero_k(float* __restrict__ pooled,
                                              u16* __restrict__ xpadT) {
    int b = blockIdx.x, t = threadIdx.x;
    pooled[b * 256 + t] = 0.0f;
    u16x8 z = {0, 0, 0, 0, 0, 0, 0, 0};
    u16* r0 = xpadT + ((size_t)(b * HP + 0)) * WP * NC;
    u16* r1 = xpadT + ((size_t)(b * HP + 57)) * WP * NC;
    #pragma unroll
    for (int i = 0; i < 8; ++i) {
        *(u16x8*)&r0[(i * 256 + t) * 8] = z;
        *(u16x8*)&r1[(i * 256 + t) * 8] = z;
    }
}

// ---------------------------------------------------------------- kernel 1
// One block per (b,h): NCHW fp32 -> padded NHWC bf16 row transpose + pooling
// partial sums (computed from the LDS tile; no shuffles).
// LDS tile: u16 [64 w][32 slots of 8c], physical slot = s ^ (w>>2).
__global__ __launch_bounds__(256) void transpose_pool_k(const float* __restrict__ x,
                                                        u16* __restrict__ xpadT,
                                                        float* __restrict__ pooled) {
    __shared__ u16 tile[64 * 256];          // 32 KB
    int b = blockIdx.x / 56;
    int h = blockIdx.x % 56;
    int t = threadIdx.x;

    // ---- write phase: coalesced float4 reads along w
    int w4 = t & 15, c_sub = t >> 4;        // w4: 0..13 valid (56 w), c_sub: 0..15
    if (w4 < 14) {
        const float* xp = x + ((size_t)b * NC + c_sub) * NP + (size_t)h * NW + w4 * 4;
        #pragma unroll
        for (int it = 0; it < 16; ++it) {
            int c = it * 16 + c_sub;
            f32x4 v = *(const f32x4*)(xp + (size_t)it * 16 * NP);
            int key = w4;                    // (w>>2) for all 4 written rows
            int base = ((c >> 3) ^ key) * 8 + (c & 7);
            #pragma unroll
            for (int i = 0; i < 4; ++i)
                tile[(w4 * 4 + i) * 256 + base] = f2bf(v[i]);
        }
    }
    __syncthreads();

    // ---- global write phase: u16x8 along c, 1 KB/wave
    {
        int c8 = t & 31, whi = t >> 5;       // whi: 0..7
        u16* orow = xpadT + ((size_t)(b * HP + h + 1)) * WP * NC;
        #pragma unroll
        for (int j = 0; j < 8; ++j) {
            int wp = whi * 8 + j;
            u16x8 v = {0, 0, 0, 0, 0, 0, 0, 0};
            if (wp >= 1 && wp <= 56) {
                int w = wp - 1;
                v = *(const u16x8*)&tile[w * 256 + ((c8 ^ (w >> 2)) * 8)];
            }
            *(u16x8*)&orow[wp * NC + c8 * 8] = v;
        }
    }

    // ---- pool phase: per-thread channel sum over the 56 w of this row
    {
        int c = t;
        int s = c >> 3, sub = c & 7;
        float sum = 0.0f;
        #pragma unroll
        for (int w = 0; w < 56; ++w) {
            u16 u = tile[w * 256 + ((s ^ (w >> 2)) * 8) + sub];
            sum += __uint_as_float(((unsigned)u) << 16);
        }
        atomicAdd(&pooled[b * 256 + c], sum);
    }
}

// ---------------------------------------------------------------- kernel 2
// routing: rt = (pooled/3136) @ proj_w^T + proj_b ; sigmoid ; avgpool(8) -> r[32][8]
__global__ __launch_bounds__(64) void routing(const float* __restrict__ pooled,
                                              const float* __restrict__ proj_w,
                                              const float* __restrict__ proj_b,
                                              float* __restrict__ r) {
    __shared__ float ps[256];
    __shared__ float sg[64];
    int b = blockIdx.x, j = threadIdx.x;
    for (int i = j; i < 256; i += 64) ps[i] = pooled[b * NC + i] * (1.0f / 3136.0f);
    __syncthreads();
    float acc = proj_b[j];
    for (int c = 0; c < 256; ++c) acc += ps[c] * proj_w[j * NC + c];
    sg[j] = 1.0f / (1.0f + expf(-acc));
    __syncthreads();
    if (j < NE) {
        float s = 0.0f;
        #pragma unroll
        for (int q = 0; q < 8; ++q) s += sg[j * 8 + q];
        r[b * NE + j] = s * 0.125f;
    }
}

// ---------------------------------------------------------------- kernel 3
// wmix[b][kk][o][c] = bf16( sum_e r[b][e] * expert_w[e][o][c][kk] )
__global__ __launch_bounds__(256) void mix_w(const float* __restrict__ expert_w,
                                             const float* __restrict__ r,
                                             u16* __restrict__ wmix) {
    __shared__ float lr[256];
    int o = blockIdx.x, c = threadIdx.x;
    lr[c] = r[c];                               // 32*8 = 256
    __syncthreads();
    float w[8][9];
    #pragma unroll
    for (int e = 0; e < 8; ++e) {
        const float* p = expert_w + ((size_t)((e * NO + o) * NC + c)) * 9;
        #pragma unroll
        for (int kk = 0; kk < 9; ++kk) w[e][kk] = p[kk];
    }
    for (int b = 0; b < NB; ++b) {
        float acc[9] = {0, 0, 0, 0, 0, 0, 0, 0, 0};
        #pragma unroll
        for (int e = 0; e < 8; ++e) {
            float rv = lr[b * 8 + e];
            #pragma unroll
            for (int kk = 0; kk < 9; ++kk) acc[kk] += rv * w[e][kk];
        }
        #pragma unroll
        for (int kk = 0; kk < 9; ++kk)
            wmix[((size_t)((b * 9 + kk) * NO + o)) * NC + c] = f2bf(acc[kk]);
    }
}

// ---------------------------------------------------------------- kernel 4
// Implicit-GEMM conv, 32x32x16 MFMA. 256 threads (4 waves).
// Per block: b, FULL o=256 (waves stacked in M: wave w owns o [w*64,w*64+64)),
// p-tile 64 (3136 = 49x64 exact; window = 4 padded rows).
// Wave tile 64x64: acc = 4 x f32x16 (64 AGPR). Per K16-step: 2 B ds_reads
// feed 4 MFMAs (131k FLOP) -- LDS-pipe work per FLOP is 2.6x lower than the
// 16x16 structure (r14 ledger: LDS pipe ~70% busy was the ceiling).
// A: DIRECT global->VGPR (A via LDS is 1:1, pure overhead). abuf[4][2],
//   pipelined 4 K16-steps (1 tap) ahead; issue slots pinned with SBAR,
//   counted VM_WAIT(6) (8 loads in flight steady; never 0 mid-chunk).
// B: LDS [256 rw][64 c] (32 KB), staged per c0=64 chunk via global_load_lds,
//   r8's exact XOR swizzle (measured zero conflicts). B-frags additionally
//   prefetched ONE kstep ahead into regs (parity ping-pong) so ds_read
//   latency hides under the previous kstep's MFMAs.
// Layouts (32x32x16): A row=l&31, k=(l>>5)*8+j; B col=l&31, same k;
// C/D col=l&31, row=(r&3)+8*(r>>2)+4*(l>>5)  [m74/m101 verified].
// Grid 1568 = 8 XCD x 196, bijective: each XCD owns 4 consecutive b.
__global__ __launch_bounds__(256, 2) void conv_k(const u16* __restrict__ wmix,
                                                 const u16* __restrict__ xpadT,
                                                 float* __restrict__ out) {
    __shared__ u16 Bs[256 * 64];       // 32 KB (the only LDS)
    char* Bsc = (char*)Bs;

    int tid  = threadIdx.x;
    int lane = tid & 63, wid = tid >> 6;     // wid 0..3
    int l31 = lane & 31, khalf = lane >> 5;

    int bid = blockIdx.x;
    int logical = (bid & 7) * 196 + (bid >> 3);
    int b  = logical / 49;
    int pt = logical % 49;
    int p0 = pt * 64;
    int h_lo = p0 / 56;                      // first image row of this tile

    const u16* apane = wmix + (size_t)b * 9 * 65536;                 // + kk*65536 + o*256 + c
    const u16* xbase = xpadT + ((size_t)(b * HP + h_lo)) * WP * NC;  // padded rows h_lo..h_lo+3

    // per-lane A base: row = wid*64 + l31 (frag0; frag1 = +32 rows = +8192 elem)
    const u16* alane = apane + (size_t)(wid * 64 + l31) * 256 + khalf * 8;

    // ---- B staging (r8 pattern): thread t covers rows t3+i*32, slot t7,
    // global source c-group pre-swizzled with key (row&7) = (t3&7).
    int t3 = tid >> 3, t7 = tid & 7;
    int bstg_src = t3 * 256 + ((t7 ^ (t3 & 7)) * 8);   // elements
    int bstg_dst = tid * 16;                            // bytes, linear
    #define STAGE_B(C0) {                                                   \
        _Pragma("unroll")                                                   \
        for (int i = 0; i < 8; ++i)                                         \
            gl_lds16(xbase + (C0) + bstg_src + i * 8192,                    \
                     Bsc + bstg_dst + i * 4096);                            \
    }

    // per-lane B row bases: pixel p = p0 + ni2*32 + l31
    int pa0 = p0 + l31;
    int pa1 = p0 + 32 + l31;
    int rwb0 = (pa0 / 56 - h_lo) * 64 + pa0 % 56;
    int rwb1 = (pa1 / 56 - h_lo) * 64 + pa1 % 56;

    // A fragment registers: abuf[slot 0..3][frag 0..1] (32 VGPR)
    bf16x8 abuf[4][2];
    #define ISSUE_A(KK, KS, C0) {                                           \
        const u16* ap_ = alane + (KK) * 65536 + (C0) + (KS) * 16;           \
        abuf[KS][0] = *(const bf16x8*)(ap_);                                \
        abuf[KS][1] = *(const bf16x8*)(ap_ + 8192);                         \
    }

    // B fragment registers: bb[parity][ni2] (16 VGPR)
    bf16x8 bb[2][2];
    #define READ_B(KK, KS, P) {                                             \
        const int dh_ = (KK) / 3, kw_ = (KK) % 3;                           \
        int rw0_ = rwb0 + dh_ * 64 + kw_;                                   \
        int rw1_ = rwb1 + dh_ * 64 + kw_;                                   \
        bb[P][0] = *(const bf16x8*)(Bsc + rw0_ * 128 +                      \
                     ((((KS) * 2 + khalf) ^ (rw0_ & 7)) << 4));             \
        bb[P][1] = *(const bf16x8*)(Bsc + rw1_ * 128 +                      \
                     ((((KS) * 2 + khalf) ^ (rw1_ & 7)) << 4));             \
    }

    // accumulators (named, all-literal indexing)
    f32x16 acc00, acc01, acc10, acc11;
    #pragma unroll
    for (int r = 0; r < 16; ++r) { acc00[r] = 0.f; acc01[r] = 0.f; acc10[r] = 0.f; acc11[r] = 0.f; }

    #define MFMA4(P, S) {                                                   \
        acc00 = __builtin_amdgcn_mfma_f32_32x32x16_bf16(abuf[S][0], bb[P][0], acc00, 0, 0, 0); \
        acc10 = __builtin_amdgcn_mfma_f32_32x32x16_bf16(abuf[S][1], bb[P][0], acc10, 0, 0, 0); \
        acc01 = __builtin_amdgcn_mfma_f32_32x32x16_bf16(abuf[S][0], bb[P][1], acc01, 0, 0, 0); \
        acc11 = __builtin_amdgcn_mfma_f32_32x32x16_bf16(abuf[S][1], bb[P][1], acc11, 0, 0, 0); \
    }

    // kstep: compute (KK,KS) on bb[P]/abuf[KS]; prefetch B(BKK,BKS)->bb[P^1];
    // prefetch A(NKK, slot KS) from NC0. Variants: _NB no B-prefetch,
    // _NA no A-prefetch (custom wait), _NANB neither.
    #define KSTEP(KK, KS, P, BKK, BKS, NKK, NC0) {                          \
        READ_B(BKK, BKS, (P) ^ 1)                                           \
        VM_WAIT(6)                                                          \
        MFMA4(P, KS)                                                        \
        ISSUE_A(NKK, KS, NC0)                                               \
        SBAR()                                                              \
    }
    #define KSTEP_NB(KK, KS, P, NKK, NC0) {                                 \
        VM_WAIT(6)                                                          \
        MFMA4(P, KS)                                                        \
        ISSUE_A(NKK, KS, NC0)                                               \
        SBAR()                                                              \
    }
    #define KSTEP_NA(KK, KS, P, BKK, BKS, WN) {                             \
        READ_B(BKK, BKS, (P) ^ 1)                                           \
        VM_WAIT(WN)                                                         \
        MFMA4(P, KS)                                                        \
    }
    #define KSTEP_NANB(KK, KS, P, WN) {                                     \
        VM_WAIT(WN)                                                         \
        MFMA4(P, KS)                                                        \
    }

    // one tap (4 ksteps), B-prefetch rolls to next tap's ks0 at the end
    #define TAPM(KK, BKK2, NKK, NC0) {                                      \
        KSTEP(KK, 0, 0, KK, 1, NKK, NC0)                                    \
        KSTEP(KK, 1, 1, KK, 2, NKK, NC0)                                    \
        KSTEP(KK, 2, 0, KK, 3, NKK, NC0)                                    \
        KSTEP(KK, 3, 1, BKK2, 0, NKK, NC0)                                  \
    }

    #define CHUNKM(C0) {                                                    \
        READ_B(0, 0, 0)                                                     \
        TAPM(0, 1, 1, C0) TAPM(1, 2, 2, C0) TAPM(2, 3, 3, C0)               \
        TAPM(3, 4, 4, C0) TAPM(4, 5, 5, C0) TAPM(5, 6, 6, C0)               \
        TAPM(6, 7, 7, C0) TAPM(7, 8, 8, C0)                                 \
        KSTEP(8, 0, 0, 8, 1, 0, (C0) + 64)                                  \
        KSTEP(8, 1, 1, 8, 2, 0, (C0) + 64)                                  \
        KSTEP(8, 2, 0, 8, 3, 0, (C0) + 64)                                  \
        KSTEP_NB(8, 3, 1, 0, (C0) + 64)                                     \
        __syncthreads();                                                    \
        STAGE_B((C0) + 64)                                                  \
        __syncthreads();                                                    \
    }
    #define CHUNK_LAST(C0) {                                                \
        READ_B(0, 0, 0)                                                     \
        TAPM(0, 1, 1, C0) TAPM(1, 2, 2, C0) TAPM(2, 3, 3, C0)               \
        TAPM(3, 4, 4, C0) TAPM(4, 5, 5, C0) TAPM(5, 6, 6, C0)               \
        TAPM(6, 7, 7, C0) TAPM(7, 8, 8, C0)                                 \
        KSTEP_NA(8, 0, 0, 8, 1, 6)                                          \
        KSTEP_NA(8, 1, 1, 8, 2, 4)                                          \
        KSTEP_NA(8, 2, 0, 8, 3, 2)                                          \
        KSTEP_NANB(8, 3, 1, 0)                                              \
    }

    // prologue: B(c0=0) staged; A tap0 slots 0-3 in flight -> barrier drains
    STAGE_B(0)
    ISSUE_A(0, 0, 0) ISSUE_A(0, 1, 0) ISSUE_A(0, 2, 0) ISSUE_A(0, 3, 0)
    __syncthreads();

    CHUNKM(0)
    CHUNKM(64)
    CHUNKM(128)
    CHUNK_LAST(192)

    #undef CHUNK_LAST
    #undef CHUNKM
    #undef TAPM
    #undef KSTEP_NANB
    #undef KSTEP_NA
    #undef KSTEP_NB
    #undef KSTEP
    #undef MFMA4
    #undef READ_B
    #undef ISSUE_A
    #undef STAGE_B

    // epilogue: 32x32 D layout: col = l31, row = (r&3) + 8*(r>>2) + 4*khalf
    float* op = out + ((size_t)(b * NO + wid * 64)) * NP + p0;
    #pragma unroll
    for (int r = 0; r < 16; ++r) {
        int row = (r & 3) + 8 * (r >> 2) + 4 * khalf;
        op[(size_t)row * NP + l31]              = acc00[r];
        op[(size_t)row * NP + 32 + l31]         = acc01[r];
        op[(size_t)(32 + row) * NP + l31]       = acc10[r];
        op[(size_t)(32 + row) * NP + 32 + l31]  = acc11[r];
    }
}

// ---------------------------------------------------------------- launch
extern "C" void kernel_launch(void* const* d_in, const int* in_sizes, int n_in,
                              void* d_out, int out_size, void* d_ws, size_t ws_size,
                              hipStream_t stream) {
    (void)in_sizes; (void)n_in; (void)out_size; (void)ws_size;
    const float* x        = (const float*)d_in[0];
    const float* proj_w   = (const float*)d_in[1];
    const float* proj_b   = (const float*)d_in[2];
    const float* expert_w = (const float*)d_in[3];
    float* out = (float*)d_out;
    char*  ws  = (char*)d_ws;

    u16*   wmix   = (u16*)(ws + WMIX_OFF);
    u16*   xpadT  = (u16*)(ws + XPT_OFF);
    float* pooled = (float*)(ws + POOL_OFF);
    float* rbuf   = (float*)(ws + RBUF_OFF);

    zero_k<<<dim3(32), dim3(256), 0, stream>>>(pooled, xpadT);
    transpose_pool_k<<<dim3(32 * 56), dim3(256), 0, stream>>>(x, xpadT, pooled);
    routing<<<dim3(32), dim3(64), 0, stream>>>(pooled, proj_w, proj_b, rbuf);
    mix_w<<<dim3(256), dim3(256), 0, stream>>>(expert_w, rbuf, wmix);
    conv_k<<<dim3(32 * 49), dim3(256), 0, stream>>>(wmix, xpadT, out);
}

// Round 16
// 764.851 us; speedup vs baseline: 1.7188x; 1.7188x over previous
//
#include <hip/hip_runtime.h>
#include <math.h>

typedef unsigned short u16;
typedef __attribute__((ext_vector_type(8))) short    bf16x8;
typedef __attribute__((ext_vector_type(8))) unsigned short u16x8;
typedef __attribute__((ext_vector_type(4))) float    f32x4;
typedef __attribute__((ext_vector_type(16))) float   f32x16;

// Problem constants
#define NB   32        // batch
#define NC   256       // in channels
#define NO   256       // out channels
#define NH   56
#define NW   56
#define NP   3136      // H*W
#define NE   8
#define NID  64
#define HP   58        // padded rows
#define WP   64        // padded row width (aligned)

// Workspace layout (bytes)
#define WMIX_OFF   0                    // u16 [32][9][256][256] = 37,748,736 B
#define XPT_OFF    37748736             // u16 [32][58][64][256] = 60,817,408 B
#define POOL_OFF   98566144             // f32 [32][256]
#define RBUF_OFF   98598912             // f32 [32][8]

__device__ __forceinline__ u16 f2bf(float f) {
    unsigned u = __float_as_uint(f);
    unsigned r = (u + 0x7FFFu + ((u >> 16) & 1u)) >> 16;   // RNE
    return (u16)r;
}

__device__ __forceinline__ void gl_lds16(const void* g, void* l) {
    __builtin_amdgcn_global_load_lds(
        (const __attribute__((address_space(1))) unsigned int*)g,
        (__attribute__((address_space(3))) unsigned int*)l, 16, 0, 0);
}

#define SBAR() __builtin_amdgcn_sched_barrier(0);
// counted wait (perf hint only; correctness is register-dep guaranteed)
#define VM_WAIT(N) { asm volatile("s_waitcnt vmcnt(" #N ")" ::: "memory"); \
                     __builtin_amdgcn_sched_barrier(0); }

// ---------------------------------------------------------------- kernel 0
// Zero pooled accumulators + the two border rows (h'=0,57) of xpadT.
__global__ __launch_bounds__(256) void zero_k(float* __restrict__ pooled,
                                              u16* __restrict__ xpadT) {
    int b = blockIdx.x, t = threadIdx.x;
    pooled[b * 256 + t] = 0.0f;
    u16x8 z = {0, 0, 0, 0, 0, 0, 0, 0};
    u16* r0 = xpadT + ((size_t)(b * HP + 0)) * WP * NC;
    u16* r1 = xpadT + ((size_t)(b * HP + 57)) * WP * NC;
    #pragma unroll
    for (int i = 0; i < 8; ++i) {
        *(u16x8*)&r0[(i * 256 + t) * 8] = z;
        *(u16x8*)&r1[(i * 256 + t) * 8] = z;
    }
}

// ---------------------------------------------------------------- kernel 1
// One block per (b,h): NCHW fp32 -> padded NHWC bf16 row transpose + pooling
// partial sums (computed from the LDS tile; no shuffles).
// LDS tile: u16 [64 w][32 slots of 8c], physical slot = s ^ (w>>2).
__global__ __launch_bounds__(256) void transpose_pool_k(const float* __restrict__ x,
                                                        u16* __restrict__ xpadT,
                                                        float* __restrict__ pooled) {
    __shared__ u16 tile[64 * 256];          // 32 KB
    int b = blockIdx.x / 56;
    int h = blockIdx.x % 56;
    int t = threadIdx.x;

    // ---- write phase: coalesced float4 reads along w
    int w4 = t & 15, c_sub = t >> 4;        // w4: 0..13 valid (56 w), c_sub: 0..15
    if (w4 < 14) {
        const float* xp = x + ((size_t)b * NC + c_sub) * NP + (size_t)h * NW + w4 * 4;
        #pragma unroll
        for (int it = 0; it < 16; ++it) {
            int c = it * 16 + c_sub;
            f32x4 v = *(const f32x4*)(xp + (size_t)it * 16 * NP);
            int key = w4;                    // (w>>2) for all 4 written rows
            int base = ((c >> 3) ^ key) * 8 + (c & 7);
            #pragma unroll
            for (int i = 0; i < 4; ++i)
                tile[(w4 * 4 + i) * 256 + base] = f2bf(v[i]);
        }
    }
    __syncthreads();

    // ---- global write phase: u16x8 along c, 1 KB/wave
    {
        int c8 = t & 31, whi = t >> 5;       // whi: 0..7
        u16* orow = xpadT + ((size_t)(b * HP + h + 1)) * WP * NC;
        #pragma unroll
        for (int j = 0; j < 8; ++j) {
            int wp = whi * 8 + j;
            u16x8 v = {0, 0, 0, 0, 0, 0, 0, 0};
            if (wp >= 1 && wp <= 56) {
                int w = wp - 1;
                v = *(const u16x8*)&tile[w * 256 + ((c8 ^ (w >> 2)) * 8)];
            }
            *(u16x8*)&orow[wp * NC + c8 * 8] = v;
        }
    }

    // ---- pool phase: per-thread channel sum over the 56 w of this row
    {
        int c = t;
        int s = c >> 3, sub = c & 7;
        float sum = 0.0f;
        #pragma unroll
        for (int w = 0; w < 56; ++w) {
            u16 u = tile[w * 256 + ((s ^ (w >> 2)) * 8) + sub];
            sum += __uint_as_float(((unsigned)u) << 16);
        }
        atomicAdd(&pooled[b * 256 + c], sum);
    }
}

// ---------------------------------------------------------------- kernel 2
// routing: rt = (pooled/3136) @ proj_w^T + proj_b ; sigmoid ; avgpool(8) -> r[32][8]
__global__ __launch_bounds__(64) void routing(const float* __restrict__ pooled,
                                              const float* __restrict__ proj_w,
                                              const float* __restrict__ proj_b,
                                              float* __restrict__ r) {
    __shared__ float ps[256];
    __shared__ float sg[64];
    int b = blockIdx.x, j = threadIdx.x;
    for (int i = j; i < 256; i += 64) ps[i] = pooled[b * NC + i] * (1.0f / 3136.0f);
    __syncthreads();
    float acc = proj_b[j];
    for (int c = 0; c < 256; ++c) acc += ps[c] * proj_w[j * NC + c];
    sg[j] = 1.0f / (1.0f + expf(-acc));
    __syncthreads();
    if (j < NE) {
        float s = 0.0f;
        #pragma unroll
        for (int q = 0; q < 8; ++q) s += sg[j * 8 + q];
        r[b * NE + j] = s * 0.125f;
    }
}

// ---------------------------------------------------------------- kernel 3
// wmix[b][kk][o][c] = bf16( sum_e r[b][e] * expert_w[e][o][c][kk] )
__global__ __launch_bounds__(256) void mix_w(const float* __restrict__ expert_w,
                                             const float* __restrict__ r,
                                             u16* __restrict__ wmix) {
    __shared__ float lr[256];
    int o = blockIdx.x, c = threadIdx.x;
    lr[c] = r[c];                               // 32*8 = 256
    __syncthreads();
    float w[8][9];
    #pragma unroll
    for (int e = 0; e < 8; ++e) {
        const float* p = expert_w + ((size_t)((e * NO + o) * NC + c)) * 9;
        #pragma unroll
        for (int kk = 0; kk < 9; ++kk) w[e][kk] = p[kk];
    }
    for (int b = 0; b < NB; ++b) {
        float acc[9] = {0, 0, 0, 0, 0, 0, 0, 0, 0};
        #pragma unroll
        for (int e = 0; e < 8; ++e) {
            float rv = lr[b * 8 + e];
            #pragma unroll
            for (int kk = 0; kk < 9; ++kk) acc[kk] += rv * w[e][kk];
        }
        #pragma unroll
        for (int kk = 0; kk < 9; ++kk)
            wmix[((size_t)((b * 9 + kk) * NO + o)) * NC + c] = f2bf(acc[kk]);
    }
}

// ---------------------------------------------------------------- kernel 4
// Implicit-GEMM conv, 32x32x16 MFMA. 256 threads (4 waves).
// Per block: b, FULL o=256 (waves stacked in M: wave w owns o [w*64,w*64+64)),
// p-tile 64 (3136 = 49x64 exact; window = 4 padded rows).
// Wave tile 64x64: acc = 4 x f32x16 (64 AGPR). Per K16-step: 2 B ds_reads
// feed 4 MFMAs (131k FLOP) -- LDS-pipe work per FLOP is 2.6x lower than the
// 16x16 structure (r14 ledger: LDS pipe ~70% busy was the ceiling).
// A: DIRECT global->VGPR (A via LDS is 1:1, pure overhead). abuf[4][2],
//   pipelined 4 K16-steps (1 tap) ahead; issue slots pinned with SBAR,
//   counted VM_WAIT(6) (8 loads in flight steady; never 0 mid-chunk).
// B: LDS [256 rw][64 c] (32 KB), staged per c0=64 chunk via global_load_lds,
//   r8's XOR swizzle. B-frags prefetched ONE kstep ahead into regs
//   (parity ping-pong) so ds_read latency hides under the prev kstep's MFMAs.
// __launch_bounds__(256, 1): r15 shipped (256,2) by mistake -> VGPR cap 128
//   < ~180 unified live set -> f32x16 accs spilled (WRITE 1.8 GB, 1270 us).
//   arg2=1 caps at 512; ~180 live -> 2 waves/SIMD, zero spill.
// Layouts (32x32x16, verified by r15's PASS): A row=l&31, k=(l>>5)*8+j;
// B col=l&31 same k; C/D col=l&31, row=(r&3)+8*(r>>2)+4*(l>>5).
// Grid 1568 = 8 XCD x 196, bijective: each XCD owns 4 consecutive b.
__global__ __launch_bounds__(256, 1) void conv_k(const u16* __restrict__ wmix,
                                                 const u16* __restrict__ xpadT,
                                                 float* __restrict__ out) {
    __shared__ u16 Bs[256 * 64];       // 32 KB (the only LDS)
    char* Bsc = (char*)Bs;

    int tid  = threadIdx.x;
    int lane = tid & 63, wid = tid >> 6;     // wid 0..3
    int l31 = lane & 31, khalf = lane >> 5;

    int bid = blockIdx.x;
    int logical = (bid & 7) * 196 + (bid >> 3);
    int b  = logical / 49;
    int pt = logical % 49;
    int p0 = pt * 64;
    int h_lo = p0 / 56;                      // first image row of this tile

    const u16* apane = wmix + (size_t)b * 9 * 65536;                 // + kk*65536 + o*256 + c
    const u16* xbase = xpadT + ((size_t)(b * HP + h_lo)) * WP * NC;  // padded rows h_lo..h_lo+3

    // per-lane A base: row = wid*64 + l31 (frag0; frag1 = +32 rows = +8192 elem)
    const u16* alane = apane + (size_t)(wid * 64 + l31) * 256 + khalf * 8;

    // ---- B staging (r8 pattern): thread t covers rows t3+i*32, slot t7,
    // global source c-group pre-swizzled with key (row&7) = (t3&7).
    int t3 = tid >> 3, t7 = tid & 7;
    int bstg_src = t3 * 256 + ((t7 ^ (t3 & 7)) * 8);   // elements
    int bstg_dst = tid * 16;                            // bytes, linear
    #define STAGE_B(C0) {                                                   \
        _Pragma("unroll")                                                   \
        for (int i = 0; i < 8; ++i)                                         \
            gl_lds16(xbase + (C0) + bstg_src + i * 8192,                    \
                     Bsc + bstg_dst + i * 4096);                            \
    }

    // per-lane B row bases: pixel p = p0 + ni2*32 + l31
    int pa0 = p0 + l31;
    int pa1 = p0 + 32 + l31;
    int rwb0 = (pa0 / 56 - h_lo) * 64 + pa0 % 56;
    int rwb1 = (pa1 / 56 - h_lo) * 64 + pa1 % 56;

    // A fragment registers: abuf[slot 0..3][frag 0..1] (32 VGPR)
    bf16x8 abuf[4][2];
    #define ISSUE_A(KK, KS, C0) {                                           \
        const u16* ap_ = alane + (KK) * 65536 + (C0) + (KS) * 16;           \
        abuf[KS][0] = *(const bf16x8*)(ap_);                                \
        abuf[KS][1] = *(const bf16x8*)(ap_ + 8192);                         \
    }

    // B fragment registers: bb[parity][ni2] (16 VGPR)
    bf16x8 bb[2][2];
    #define READ_B(KK, KS, P) {                                             \
        const int dh_ = (KK) / 3, kw_ = (KK) % 3;                           \
        int rw0_ = rwb0 + dh_ * 64 + kw_;                                   \
        int rw1_ = rwb1 + dh_ * 64 + kw_;                                   \
        bb[P][0] = *(const bf16x8*)(Bsc + rw0_ * 128 +                      \
                     ((((KS) * 2 + khalf) ^ (rw0_ & 7)) << 4));             \
        bb[P][1] = *(const bf16x8*)(Bsc + rw1_ * 128 +                      \
                     ((((KS) * 2 + khalf) ^ (rw1_ & 7)) << 4));             \
    }

    // accumulators (named, all-literal indexing)
    f32x16 acc00, acc01, acc10, acc11;
    #pragma unroll
    for (int r = 0; r < 16; ++r) { acc00[r] = 0.f; acc01[r] = 0.f; acc10[r] = 0.f; acc11[r] = 0.f; }

    #define MFMA4(P, S) {                                                   \
        acc00 = __builtin_amdgcn_mfma_f32_32x32x16_bf16(abuf[S][0], bb[P][0], acc00, 0, 0, 0); \
        acc10 = __builtin_amdgcn_mfma_f32_32x32x16_bf16(abuf[S][1], bb[P][0], acc10, 0, 0, 0); \
        acc01 = __builtin_amdgcn_mfma_f32_32x32x16_bf16(abuf[S][0], bb[P][1], acc01, 0, 0, 0); \
        acc11 = __builtin_amdgcn_mfma_f32_32x32x16_bf16(abuf[S][1], bb[P][1], acc11, 0, 0, 0); \
    }

    // kstep: compute (KK,KS) on bb[P]/abuf[KS]; prefetch B(BKK,BKS)->bb[P^1];
    // prefetch A(NKK, slot KS) from NC0. Variants: _NB no B-prefetch,
    // _NA no A-prefetch (custom wait), _NANB neither.
    #define KSTEP(KK, KS, P, BKK, BKS, NKK, NC0) {                          \
        READ_B(BKK, BKS, (P) ^ 1)                                           \
        VM_WAIT(6)                                                          \
        MFMA4(P, KS)                                                        \
        ISSUE_A(NKK, KS, NC0)                                               \
        SBAR()                                                              \
    }
    #define KSTEP_NB(KK, KS, P, NKK, NC0) {                                 \
        VM_WAIT(6)                                                          \
        MFMA4(P, KS)                                                        \
        ISSUE_A(NKK, KS, NC0)                                               \
        SBAR()                                                              \
    }
    #define KSTEP_NA(KK, KS, P, BKK, BKS, WN) {                             \
        READ_B(BKK, BKS, (P) ^ 1)                                           \
        VM_WAIT(WN)                                                         \
        MFMA4(P, KS)                                                        \
    }
    #define KSTEP_NANB(KK, KS, P, WN) {                                     \
        VM_WAIT(WN)                                                         \
        MFMA4(P, KS)                                                        \
    }

    // one tap (4 ksteps), B-prefetch rolls to next tap's ks0 at the end
    #define TAPM(KK, BKK2, NKK, NC0) {                                      \
        KSTEP(KK, 0, 0, KK, 1, NKK, NC0)                                    \
        KSTEP(KK, 1, 1, KK, 2, NKK, NC0)                                    \
        KSTEP(KK, 2, 0, KK, 3, NKK, NC0)                                    \
        KSTEP(KK, 3, 1, BKK2, 0, NKK, NC0)                                  \
    }

    #define CHUNKM(C0) {                                                    \
        READ_B(0, 0, 0)                                                     \
        TAPM(0, 1, 1, C0) TAPM(1, 2, 2, C0) TAPM(2, 3, 3, C0)               \
        TAPM(3, 4, 4, C0) TAPM(4, 5, 5, C0) TAPM(5, 6, 6, C0)               \
        TAPM(6, 7, 7, C0) TAPM(7, 8, 8, C0)                                 \
        KSTEP(8, 0, 0, 8, 1, 0, (C0) + 64)                                  \
        KSTEP(8, 1, 1, 8, 2, 0, (C0) + 64)                                  \
        KSTEP(8, 2, 0, 8, 3, 0, (C0) + 64)                                  \
        KSTEP_NB(8, 3, 1, 0, (C0) + 64)                                     \
        __syncthreads();                                                    \
        STAGE_B((C0) + 64)                                                  \
        __syncthreads();                                                    \
    }
    #define CHUNK_LAST(C0) {                                                \
        READ_B(0, 0, 0)                                                     \
        TAPM(0, 1, 1, C0) TAPM(1, 2, 2, C0) TAPM(2, 3, 3, C0)               \
        TAPM(3, 4, 4, C0) TAPM(4, 5, 5, C0) TAPM(5, 6, 6, C0)               \
        TAPM(6, 7, 7, C0) TAPM(7, 8, 8, C0)                                 \
        KSTEP_NA(8, 0, 0, 8, 1, 6)                                          \
        KSTEP_NA(8, 1, 1, 8, 2, 4)                                          \
        KSTEP_NA(8, 2, 0, 8, 3, 2)                                          \
        KSTEP_NANB(8, 3, 1, 0)                                              \
    }

    // prologue: B(c0=0) staged; A tap0 slots 0-3 in flight -> barrier drains
    STAGE_B(0)
    ISSUE_A(0, 0, 0) ISSUE_A(0, 1, 0) ISSUE_A(0, 2, 0) ISSUE_A(0, 3, 0)
    __syncthreads();

    CHUNKM(0)
    CHUNKM(64)
    CHUNKM(128)
    CHUNK_LAST(192)

    #undef CHUNK_LAST
    #undef CHUNKM
    #undef TAPM
    #undef KSTEP_NANB
    #undef KSTEP_NA
    #undef KSTEP_NB
    #undef KSTEP
    #undef MFMA4
    #undef READ_B
    #undef ISSUE_A
    #undef STAGE_B

    // epilogue: 32x32 D layout: col = l31, row = (r&3) + 8*(r>>2) + 4*khalf
    float* op = out + ((size_t)(b * NO + wid * 64)) * NP + p0;
    #pragma unroll
    for (int r = 0; r < 16; ++r) {
        int row = (r & 3) + 8 * (r >> 2) + 4 * khalf;
        op[(size_t)row * NP + l31]              = acc00[r];
        op[(size_t)row * NP + 32 + l31]         = acc01[r];
        op[(size_t)(32 + row) * NP + l31]       = acc10[r];
        op[(size_t)(32 + row) * NP + 32 + l31]  = acc11[r];
    }
}

// ---------------------------------------------------------------- launch
extern "C" void kernel_launch(void* const* d_in, const int* in_sizes, int n_in,
                              void* d_out, int out_size, void* d_ws, size_t ws_size,
                              hipStream_t stream) {
    (void)in_sizes; (void)n_in; (void)out_size; (void)ws_size;
    const float* x        = (const float*)d_in[0];
    const float* proj_w   = (const float*)d_in[1];
    const float* proj_b   = (const float*)d_in[2];
    const float* expert_w = (const float*)d_in[3];
    float* out = (float*)d_out;
    char*  ws  = (char*)d_ws;

    u16*   wmix   = (u16*)(ws + WMIX_OFF);
    u16*   xpadT  = (u16*)(ws + XPT_OFF);
    float* pooled = (float*)(ws + POOL_OFF);
    float* rbuf   = (float*)(ws + RBUF_OFF);

    zero_k<<<dim3(32), dim3(256), 0, stream>>>(pooled, xpadT);
    transpose_pool_k<<<dim3(32 * 56), dim3(256), 0, stream>>>(x, xpadT, pooled);
    routing<<<dim3(32), dim3(64), 0, stream>>>(pooled, proj_w, proj_b, rbuf);
    mix_w<<<dim3(256), dim3(256), 0, stream>>>(expert_w, rbuf, wmix);
    conv_k<<<dim3(32 * 49), dim3(256), 0, stream>>>(wmix, xpadT, out);
}